// Round 1
// baseline (961.949 us; speedup 1.0000x reference)
//
#include <hip/hip_runtime.h>
#include <hip/hip_cooperative_groups.h>
#include <math.h>

namespace cg = cooperative_groups;

typedef unsigned short u16;
typedef unsigned int u32;
typedef __attribute__((ext_vector_type(8))) short s16x8;
typedef __attribute__((ext_vector_type(4))) float f32x4;

__device__ __forceinline__ float bf2f(u16 u) { return __uint_as_float(((u32)u) << 16); }
__device__ __forceinline__ u16 f2bf(float f) {
    u32 u = __float_as_uint(f);
    return (u16)((u + 0x7fffu + ((u >> 16) & 1u)) >> 16);  // RNE
}

union U4 { u32 u[4]; s16x8 v; };

__device__ __forceinline__ s16x8 pack_hi(f32x4 x0, f32x4 x1) {
    U4 r;
    r.u[0] = (__float_as_uint(x0.y) & 0xFFFF0000u) | (__float_as_uint(x0.x) >> 16);
    r.u[1] = (__float_as_uint(x0.w) & 0xFFFF0000u) | (__float_as_uint(x0.z) >> 16);
    r.u[2] = (__float_as_uint(x1.y) & 0xFFFF0000u) | (__float_as_uint(x1.x) >> 16);
    r.u[3] = (__float_as_uint(x1.w) & 0xFFFF0000u) | (__float_as_uint(x1.z) >> 16);
    return r.v;
}
__device__ __forceinline__ s16x8 pack_lo(f32x4 x0, f32x4 x1) {
    float e0 = x0.x - __uint_as_float(__float_as_uint(x0.x) & 0xFFFF0000u);
    float e1 = x0.y - __uint_as_float(__float_as_uint(x0.y) & 0xFFFF0000u);
    float e2 = x0.z - __uint_as_float(__float_as_uint(x0.z) & 0xFFFF0000u);
    float e3 = x0.w - __uint_as_float(__float_as_uint(x0.w) & 0xFFFF0000u);
    float e4 = x1.x - __uint_as_float(__float_as_uint(x1.x) & 0xFFFF0000u);
    float e5 = x1.y - __uint_as_float(__float_as_uint(x1.y) & 0xFFFF0000u);
    float e6 = x1.z - __uint_as_float(__float_as_uint(x1.z) & 0xFFFF0000u);
    float e7 = x1.w - __uint_as_float(__float_as_uint(x1.w) & 0xFFFF0000u);
    U4 r;
    r.u[0] = (__float_as_uint(e1) & 0xFFFF0000u) | (__float_as_uint(e0) >> 16);
    r.u[1] = (__float_as_uint(e3) & 0xFFFF0000u) | (__float_as_uint(e2) >> 16);
    r.u[2] = (__float_as_uint(e5) & 0xFFFF0000u) | (__float_as_uint(e4) >> 16);
    r.u[3] = (__float_as_uint(e7) & 0xFFFF0000u) | (__float_as_uint(e6) >> 16);
    return r.v;
}

#define BSHIFT 9
#define BSIZE 512
#define BCAP 10240  // entries per bin region; mean 8192, sigma ~90

struct MegaArgs {
    const float* x;
    const int* ei;
    const float* eps;
    const float* w[6];  // We1, We2, Wmu, Wlv, Wd1, Wd2
    const float* be1; const float* be2; const float* bmu;
    const float* blv; const float* bd1; const float* bd2;
    int* bin_cursor; int* cursor;
    float* dinv; int* row_start; int* cnt;
    int2* edges;
    u16* R1; u16* AZu; u16* B2; u32* binned; u16* Wpk;
    float* out_d; float* out_mu; float* out_lv;
    int N, E, NB;
};

// ---------------- phase: weight pre-pack (MFMA B-fragment order) + cursor zero ----------------

__device__ __forceinline__ void ph_pack(const MegaArgs& A, int G, int bid, int t) {
    if (bid == 0 && t < 256) A.bin_cursor[t] = 0;  // covers cursor at +128
    const int Ks[6] = {128, 128, 64, 64, 64, 128};
    const int Ms[6] = {128, 64, 64, 64, 128, 128};
    const int Off[6] = {0, 16384, 24576, 28672, 32768, 40960};
    for (int g = bid; g < 384; g += G) {
        int s = g >> 6;
        int id = (g & 63) * 256 + t;
        int K = Ks[s], M = Ms[s];
        if (id < K * M) {
            int ms = (M == 128) ? 7 : 6;
            int k = id >> ms, c = id & (M - 1);
            int chunk = k >> 5, j = k & 7, lq = (k >> 3) & 3;
            int ct = c >> 4, ln = (c & 15) + (lq << 4);
            A.Wpk[Off[s] + (chunk * (M >> 4) + ct) * 512 + ln * 8 + j] = f2bf(A.w[s][id]);
        }
    }
}

// ---------------- phase: bin edges by dst>>9, 4B packed (dst_local<<17 | src) ----------------

__device__ __forceinline__ void ph_bin(const MegaArgs& A, int c, int t, int* hist, int* base_l) {
    const int e0 = c * 4096;
    int sreg[16], dreg[16];
#pragma unroll
    for (int j = 0; j < 16; ++j) {
        int e = e0 + j * 256 + t;
        if (e < A.E) {
            sreg[j] = A.ei[e];
            dreg[j] = A.ei[A.E + e];
        } else {
            dreg[j] = -1;
        }
    }
    if (t < A.NB) hist[t] = 0;
    __syncthreads();
#pragma unroll
    for (int j = 0; j < 16; ++j)
        if (dreg[j] >= 0) atomicAdd(&hist[dreg[j] >> BSHIFT], 1);
    __syncthreads();
    if (t < A.NB) {
        base_l[t] = atomicAdd(&A.bin_cursor[t], hist[t]);
        hist[t] = 0;
    }
    __syncthreads();
#pragma unroll
    for (int j = 0; j < 16; ++j)
        if (dreg[j] >= 0) {
            int b = dreg[j] >> BSHIFT;
            int pos = base_l[b] + atomicAdd(&hist[b], 1);
            if (pos < BCAP) A.binned[(size_t)b * BCAP + pos] = ((u32)(dreg[j] & (BSIZE - 1)) << 17) | (u32)sreg[j];
        }
}

// ---------------- phase: per-bin count, pad-16 prefix scan, one cursor atomic ----------------

__device__ __forceinline__ void ph_cnt(const MegaArgs& A, int b, int t, int* cnt_l, int* wave_sum, int* base_s) {
    const int lane = t & 63, w = t >> 6;
    cnt_l[t] = 0;
    cnt_l[t + 256] = 0;
    __syncthreads();
    const int n = min(A.bin_cursor[b], BCAP);
    for (int i = t; i < n; i += 256) atomicAdd(&cnt_l[A.binned[(size_t)b * BCAP + i] >> 17], 1);
    __syncthreads();
    int c0 = cnt_l[2 * t], c1 = cnt_l[2 * t + 1];
    int p0 = (c0 + 15) & ~15, p1 = (c1 + 15) & ~15;
    int s = p0 + p1;
    int incl = s;
#pragma unroll
    for (int o = 1; o < 64; o <<= 1) {
        int v = __shfl_up(incl, o, 64);
        if (lane >= o) incl += v;
    }
    if (lane == 63) wave_sum[w] = incl;
    __syncthreads();
    if (t == 0) {
        int acc = 0;
#pragma unroll
        for (int i = 0; i < 4; ++i) {
            int v = wave_sum[i];
            wave_sum[i] = acc;
            acc += v;
        }
        *base_s = atomicAdd(A.cursor, acc);
    }
    __syncthreads();
    int excl = incl - s + wave_sum[w] + *base_s;
    int v0 = b * BSIZE + 2 * t;
    if (v0 < A.N) {
        A.cnt[v0] = c0;
        A.dinv[v0] = rsqrtf((float)(c0 + 1));
        A.row_start[v0] = excl;
    }
    if (v0 + 1 < A.N) {
        A.cnt[v0 + 1] = c1;
        A.dinv[v0 + 1] = rsqrtf((float)(c1 + 1));
        A.row_start[v0 + 1] = excl + p0;
    }
}

// ---------------- phase: per-bin scatter (src, w) + pad writes ----------------

__device__ __forceinline__ void ph_scatter(const MegaArgs& A, int b, int t, float* dv_l, int* rs_l, int* fill_l) {
#pragma unroll
    for (int hh = 0; hh < 2; ++hh) {
        int d = t + hh * 256;
        int v = b * BSIZE + d;
        bool ok = v < A.N;
        dv_l[d] = ok ? A.dinv[v] : 0.f;
        rs_l[d] = ok ? A.row_start[v] : 0;
        fill_l[d] = 0;
    }
    __syncthreads();
    const int n = min(A.bin_cursor[b], BCAP);
    for (int i = t; i < n; i += 256) {
        u32 e = A.binned[(size_t)b * BCAP + i];
        int dl = e >> 17;
        int src = e & 0x1FFFF;
        float wgt = A.dinv[src] * dv_l[dl];
        int pos = rs_l[dl] + atomicAdd(&fill_l[dl], 1);
        A.edges[pos] = make_int2(src, __float_as_int(wgt));
    }
    __syncthreads();
#pragma unroll
    for (int hh = 0; hh < 2; ++hh) {
        int d = t + hh * 256;
        int v = b * BSIZE + d;
        if (v >= A.N) continue;
        int c = fill_l[d];
        int pc = (c + 15) & ~15;
        for (int j = c; j < pc; ++j) A.edges[rs_l[d] + j] = make_int2(0, 0);
    }
}

// ---------------- phase: MFMA GEMM, B fragments from global (pre-packed), tile-stride ----------------

template <int K, int M, int RT, int NSET, int CB, bool XBF16, bool OUT_BF16, bool BREL>
__device__ void ph_gemm(const void* __restrict__ Xv, const u16* __restrict__ Bpk,
                        const float* __restrict__ b0, const float* __restrict__ b1,
                        const float* __restrict__ eps, void* __restrict__ Y0,
                        float* __restrict__ Y1, u16* __restrict__ Z, int N, int RB,
                        int G, int bid, int t) {
    constexpr int CH = K / 32;
    constexpr int TPM = M >> 4;
    constexpr int SETSTRIDE = CH * TPM * 512;
    const int lane = t & 63, w = t >> 6;
    const int l15 = lane & 15, q = lane >> 4;
    for (int tt = bid; tt < CB * RB; tt += G) {
        const int col0 = (CB == 2) ? ((tt & 1) * 64) : 0;
        const int row0 = ((CB == 2) ? (tt >> 1) : tt) * (RT * 64);

        s16x8 Bfr[NSET * CH * 4];
#pragma unroll
        for (int s = 0; s < NSET; ++s)
#pragma unroll
            for (int ch = 0; ch < CH; ++ch)
#pragma unroll
                for (int ct = 0; ct < 4; ++ct)
                    Bfr[(s * CH + ch) * 4 + ct] =
                        *(const s16x8*)&Bpk[(size_t)s * SETSTRIDE + ((ch * TPM) + (col0 >> 4) + ct) * 512 + lane * 8];

        f32x4 acc[NSET][RT][4];
#pragma unroll
        for (int s = 0; s < NSET; ++s)
#pragma unroll
            for (int rt = 0; rt < RT; ++rt)
#pragma unroll
                for (int ct = 0; ct < 4; ++ct) acc[s][rt][ct] = 0.f;

#pragma unroll
        for (int ch = 0; ch < CH; ++ch) {
#pragma unroll
            for (int rt = 0; rt < RT; ++rt) {
                int r = row0 + (w * RT + rt) * 16 + l15;
                r = r < N ? r : N - 1;
                s16x8 ah, al;
                if (XBF16) {
                    ah = *(const s16x8*)((const u16*)Xv + (size_t)r * K + (ch << 5) + (q << 3));
                } else {
                    const float* xp = (const float*)Xv + (size_t)r * K + (ch << 5) + (q << 3);
                    f32x4 x0 = *(const f32x4*)xp;
                    f32x4 x1 = *(const f32x4*)(xp + 4);
                    ah = pack_hi(x0, x1);
                    al = pack_lo(x0, x1);
                }
#pragma unroll
                for (int s = 0; s < NSET; ++s)
#pragma unroll
                    for (int ct = 0; ct < 4; ++ct) {
                        int fb = (s * CH + ch) * 4 + ct;
                        acc[s][rt][ct] = __builtin_amdgcn_mfma_f32_16x16x32_bf16(ah, Bfr[fb], acc[s][rt][ct], 0, 0, 0);
                        if (!XBF16)
                            acc[s][rt][ct] = __builtin_amdgcn_mfma_f32_16x16x32_bf16(al, Bfr[fb], acc[s][rt][ct], 0, 0, 0);
                    }
            }
        }

#pragma unroll
        for (int rt = 0; rt < RT; ++rt)
#pragma unroll
            for (int ct = 0; ct < 4; ++ct)
#pragma unroll
                for (int reg = 0; reg < 4; ++reg) {
                    int row = row0 + (w * RT + rt) * 16 + q * 4 + reg;
                    if (row >= N) continue;
                    int col = col0 + ct * 16 + l15;
                    if (NSET == 1) {
                        float v = acc[0][rt][ct][reg];
                        if (BREL) v = fmaxf(v + b0[col], 0.f);
                        if (OUT_BF16)
                            ((u16*)Y0)[(size_t)row * M + col] = f2bf(v);
                        else
                            ((float*)Y0)[(size_t)row * M + col] = v;
                    } else {
                        float mu = acc[0][rt][ct][reg] + b0[col];
                        float lv = acc[1][rt][ct][reg] + b1[col];
                        size_t o = (size_t)row * 64 + col;
                        ((float*)Y0)[o] = mu;
                        Y1[o] = lv;
                        Z[o] = f2bf(mu + eps[o] * expf(0.5f * lv));
                    }
                }
    }
}

// ---------------- phase: CSR aggregation, pad-16 buckets, 16-deep gather pipeline ----------------

template <bool RELU, bool OUT_BF16>
__device__ void ph_agg128(const MegaArgs& A, const u16* __restrict__ hin, const float* __restrict__ bias,
                          void* __restrict__ out, int G, int bid, int t) {
    const int w = t >> 6, lane = t & 63;
    const int AB = (A.N + 3) >> 2;
    const u32* hp = (const u32*)hin;
    for (int g = bid; g < AB; g += G) {
        const int v = g * 4 + w;
        if (v >= A.N) continue;
        const int start = __builtin_amdgcn_readfirstlane(A.row_start[v]);
        const int c = __builtin_amdgcn_readfirstlane(A.cnt[v]);
        const int pc = (c + 15) & ~15;
        float a0 = 0.f, a1 = 0.f;
        if (pc) {
            int2 e[16];
#pragma unroll
            for (int j = 0; j < 16; ++j) e[j] = A.edges[start + j];
            for (int i = 0; i < pc; i += 16) {
                u32 h[16];
                float wv[16];
#pragma unroll
                for (int j = 0; j < 16; ++j) {
                    h[j] = hp[(size_t)e[j].x * 64 + lane];
                    wv[j] = __int_as_float(e[j].y);
                }
                if (i + 16 < pc) {
#pragma unroll
                    for (int j = 0; j < 16; ++j) e[j] = A.edges[start + i + 16 + j];
                }
#pragma unroll
                for (int j = 0; j < 16; ++j) {
                    a0 = fmaf(wv[j], bf2f((u16)h[j]), a0);
                    a1 = fmaf(wv[j], bf2f((u16)(h[j] >> 16)), a1);
                }
            }
        }
        float dv = A.dinv[v], sw = dv * dv;
        u32 hs = hp[(size_t)v * 64 + lane];
        a0 = fmaf(sw, bf2f((u16)hs), a0);
        a1 = fmaf(sw, bf2f((u16)(hs >> 16)), a1);
        float2 bp = ((const float2*)bias)[lane];
        a0 += bp.x;
        a1 += bp.y;
        if (RELU) { a0 = fmaxf(a0, 0.f); a1 = fmaxf(a1, 0.f); }
        if (OUT_BF16)
            ((u32*)out)[(size_t)v * 64 + lane] = (u32)f2bf(a0) | ((u32)f2bf(a1) << 16);
        else
            ((float2*)out)[(size_t)v * 64 + lane] = make_float2(a0, a1);
    }
}

template <bool HASB>
__device__ void ph_agg64(const MegaArgs& A, const u16* __restrict__ hin, const float* __restrict__ bias,
                         float* __restrict__ out, int G, int bid, int t) {
    const int w = t >> 6, lane = t & 63;
    const int AB = (A.N + 3) >> 2;
    for (int g = bid; g < AB; g += G) {
        const int v = g * 4 + w;
        if (v >= A.N) continue;
        const int start = __builtin_amdgcn_readfirstlane(A.row_start[v]);
        const int c = __builtin_amdgcn_readfirstlane(A.cnt[v]);
        const int pc = (c + 15) & ~15;
        float a0 = 0.f;
        if (pc) {
            int2 e[16];
#pragma unroll
            for (int j = 0; j < 16; ++j) e[j] = A.edges[start + j];
            for (int i = 0; i < pc; i += 16) {
                u16 h[16];
                float wv[16];
#pragma unroll
                for (int j = 0; j < 16; ++j) {
                    h[j] = hin[(size_t)e[j].x * 64 + lane];
                    wv[j] = __int_as_float(e[j].y);
                }
                if (i + 16 < pc) {
#pragma unroll
                    for (int j = 0; j < 16; ++j) e[j] = A.edges[start + i + 16 + j];
                }
#pragma unroll
                for (int j = 0; j < 16; ++j) a0 = fmaf(wv[j], bf2f(h[j]), a0);
            }
        }
        float dv = A.dinv[v];
        a0 = fmaf(dv * dv, bf2f(hin[(size_t)v * 64 + lane]), a0);
        if (HASB) a0 += bias[lane];
        out[(size_t)v * 64 + lane] = a0;
    }
}

// ---------------- the mega kernel ----------------

__global__ __launch_bounds__(256, 3) void k_mega(MegaArgs A) {
    const int G = gridDim.x, bid = blockIdx.x, t = threadIdx.x;
    __shared__ alignas(16) int smem[1600];  // max user: scatter 1536 ints
    cg::grid_group gg = cg::this_grid();

    const int RB128 = (A.N + 127) >> 7;
    const int RB64 = (A.N + 63) >> 6;

    // A: zero cursors + pack weights
    ph_pack(A, G, bid, t);
    gg.sync();

    // B: bin edges (196 blocks) || encoder GEMM1 x@We1 -> R1 (remaining blocks)
    {
        const int C = (A.E + 4095) >> 12;
        if (bid < C)
            ph_bin(A, bid, t, smem, smem + 128);
        else
            ph_gemm<128, 128, 2, 1, 2, false, true, false>(A.x, A.Wpk, nullptr, nullptr, nullptr,
                                                           A.R1, nullptr, nullptr, A.N, RB128, G - C, bid - C, t);
    }
    gg.sync();

    // C: per-bin count + alloc
    if (bid < A.NB) ph_cnt(A, bid, t, smem, smem + 512, smem + 520);
    gg.sync();

    // D: per-bin scatter
    if (bid < A.NB) ph_scatter(A, bid, t, (float*)smem, smem + 512, smem + 1024);
    gg.sync();

    // E: agg128 + be1 + relu -> AZu (bf16)
    ph_agg128<true, true>(A, A.R1, A.be1, A.AZu, G, bid, t);
    gg.sync();

    // F: encoder GEMM2 AZu@We2 -> R1 (bf16)
    ph_gemm<128, 64, 1, 1, 1, true, true, false>(A.AZu, A.Wpk + 16384, nullptr, nullptr, nullptr,
                                                 A.R1, nullptr, nullptr, A.N, RB64, G, bid, t);
    gg.sync();

    // G: agg64 + be2 -> H2 (f32, reuses out_d)
    ph_agg64<true>(A, A.R1, A.be2, A.out_d, G, bid, t);
    gg.sync();

    // H: mu/logvar GEMM (NSET=2) + reparameterize -> out_mu, out_lv, z in R1 (bf16)
    ph_gemm<64, 64, 1, 2, 1, false, false, false>(A.out_d, A.Wpk + 24576, A.bmu, A.blv, A.eps,
                                                  A.out_mu, A.out_lv, A.R1, A.N, RB64, G, bid, t);
    gg.sync();

    // I: decoder agg64 (agg-first, no bias) z -> AZf (f32, aliases AZu)
    ph_agg64<false>(A, A.R1, nullptr, (float*)A.AZu, G, bid, t);
    gg.sync();

    // J: decoder GEMM1 AZf@Wd1 + bd1 + relu -> B2 (bf16)  [separate buffer: kills in-place race]
    ph_gemm<64, 128, 2, 1, 2, false, true, true>((const float*)A.AZu, A.Wpk + 32768, A.bd1, nullptr, nullptr,
                                                 A.B2, nullptr, nullptr, A.N, RB128, G, bid, t);
    gg.sync();

    // K: decoder GEMM2 B2@Wd2 -> R1 (bf16)
    ph_gemm<128, 128, 2, 1, 2, true, true, false>(A.B2, A.Wpk + 40960, nullptr, nullptr, nullptr,
                                                  A.R1, nullptr, nullptr, A.N, RB128, G, bid, t);
    gg.sync();

    // L: final agg128 + bd2 -> out_d (f32)
    ph_agg128<false, false>(A, A.R1, A.bd2, A.out_d, G, bid, t);
}

// ---------------- launch ----------------

extern "C" void kernel_launch(void* const* d_in, const int* in_sizes, int n_in,
                              void* d_out, int out_size, void* d_ws, size_t ws_size,
                              hipStream_t stream) {
    const int N = in_sizes[0] / 128;  // 50000
    const int E = in_sizes[1] / 2;    // 800000
    const int ECAP = E + 16 * N;      // pad-16 worst case
    const int NB = (N + BSIZE - 1) >> BSHIFT;  // 98

    // ws: bin_cursor(128) | cursor(1)+pad | dinv(N) | row_start(N) | cnt(N)
    //   | edges(ECAP int2) | R1(u16 N*128) | AZu(u16 N*128, aliases binned + AZf) | B2(u16 N*128) | Wpk
    int* bin_cursor = (int*)d_ws;
    int* cursor = bin_cursor + 128;
    float* dinv = (float*)(bin_cursor + 256);
    int* row_start = (int*)(dinv + N);
    int* cnt = row_start + N;
    int2* edges = (int2*)(cnt + N);
    u16* R1 = (u16*)(edges + ECAP);
    u16* AZu = R1 + (size_t)N * 128;
    u16* B2 = AZu + (size_t)N * 128;
    u16* Wpk = B2 + (size_t)N * 128;
    u32* binned = (u32*)AZu;  // alias: dead once scatter completes

    float* out_d = (float*)d_out;
    float* out_mu = out_d + (size_t)N * 128;
    float* out_lv = out_mu + (size_t)N * 64;

    MegaArgs A;
    A.x = (const float*)d_in[0];
    A.ei = (const int*)d_in[1];
    A.eps = (const float*)d_in[2];
    A.w[0] = (const float*)d_in[3];   // We1
    A.be1 = (const float*)d_in[4];
    A.w[1] = (const float*)d_in[5];   // We2
    A.be2 = (const float*)d_in[6];
    A.w[2] = (const float*)d_in[7];   // Wmu
    A.bmu = (const float*)d_in[8];
    A.w[3] = (const float*)d_in[9];   // Wlv
    A.blv = (const float*)d_in[10];
    A.w[4] = (const float*)d_in[11];  // Wd1
    A.bd1 = (const float*)d_in[12];
    A.w[5] = (const float*)d_in[13];  // Wd2
    A.bd2 = (const float*)d_in[14];
    A.bin_cursor = bin_cursor;
    A.cursor = cursor;
    A.dinv = dinv;
    A.row_start = row_start;
    A.cnt = cnt;
    A.edges = edges;
    A.R1 = R1;
    A.AZu = AZu;
    A.B2 = B2;
    A.binned = binned;
    A.Wpk = Wpk;
    A.out_d = out_d;
    A.out_mu = out_mu;
    A.out_lv = out_lv;
    A.N = N;
    A.E = E;
    A.NB = NB;

    static int nblk = 0;
    if (nblk == 0) {
        hipDeviceProp_t prop{};
        hipGetDeviceProperties(&prop, 0);
        int bpc = 0;
        hipOccupancyMaxActiveBlocksPerMultiprocessor(&bpc, reinterpret_cast<const void*>(k_mega), 256, 0);
        if (bpc < 1) bpc = 1;
        int cu = prop.multiProcessorCount > 0 ? prop.multiProcessorCount : 256;
        nblk = cu * bpc;
    }

    void* args[] = {(void*)&A};
    hipLaunchCooperativeKernel(reinterpret_cast<const void*>(k_mega), dim3(nblk), dim3(256), args, 0, stream);
}

// Round 2
// 327.663 us; speedup vs baseline: 2.9358x; 2.9358x over previous
//
#include <hip/hip_runtime.h>
#include <math.h>

typedef unsigned short u16;
typedef unsigned int u32;
typedef __attribute__((ext_vector_type(8))) short s16x8;
typedef __attribute__((ext_vector_type(4))) float f32x4;

__device__ __forceinline__ float bf2f(u16 u) { return __uint_as_float(((u32)u) << 16); }
__device__ __forceinline__ u16 f2bf(float f) {
    u32 u = __float_as_uint(f);
    return (u16)((u + 0x7fffu + ((u >> 16) & 1u)) >> 16);  // RNE
}

union U4 { u32 u[4]; s16x8 v; };

__device__ __forceinline__ s16x8 pack_hi(f32x4 x0, f32x4 x1) {
    U4 r;
    r.u[0] = (__float_as_uint(x0.y) & 0xFFFF0000u) | (__float_as_uint(x0.x) >> 16);
    r.u[1] = (__float_as_uint(x0.w) & 0xFFFF0000u) | (__float_as_uint(x0.z) >> 16);
    r.u[2] = (__float_as_uint(x1.y) & 0xFFFF0000u) | (__float_as_uint(x1.x) >> 16);
    r.u[3] = (__float_as_uint(x1.w) & 0xFFFF0000u) | (__float_as_uint(x1.z) >> 16);
    return r.v;
}
__device__ __forceinline__ s16x8 pack_lo(f32x4 x0, f32x4 x1) {
    float e0 = x0.x - __uint_as_float(__float_as_uint(x0.x) & 0xFFFF0000u);
    float e1 = x0.y - __uint_as_float(__float_as_uint(x0.y) & 0xFFFF0000u);
    float e2 = x0.z - __uint_as_float(__float_as_uint(x0.z) & 0xFFFF0000u);
    float e3 = x0.w - __uint_as_float(__float_as_uint(x0.w) & 0xFFFF0000u);
    float e4 = x1.x - __uint_as_float(__float_as_uint(x1.x) & 0xFFFF0000u);
    float e5 = x1.y - __uint_as_float(__float_as_uint(x1.y) & 0xFFFF0000u);
    float e6 = x1.z - __uint_as_float(__float_as_uint(x1.z) & 0xFFFF0000u);
    float e7 = x1.w - __uint_as_float(__float_as_uint(x1.w) & 0xFFFF0000u);
    U4 r;
    r.u[0] = (__float_as_uint(e1) & 0xFFFF0000u) | (__float_as_uint(e0) >> 16);
    r.u[1] = (__float_as_uint(e3) & 0xFFFF0000u) | (__float_as_uint(e2) >> 16);
    r.u[2] = (__float_as_uint(e5) & 0xFFFF0000u) | (__float_as_uint(e4) >> 16);
    r.u[3] = (__float_as_uint(e7) & 0xFFFF0000u) | (__float_as_uint(e6) >> 16);
    return r.v;
}

#define BSHIFT 9
#define BSIZE 512
#define BCAP 10240  // entries per bin region; mean 8192, sigma ~90

struct PackArgs { const float* w[6]; };

// ---------------- weight pre-pack into MFMA B-fragment order (bf16 RNE) ----------------

__device__ __forceinline__ void pack_body(const PackArgs& pa, u16* __restrict__ out, int g, int t) {
    const int Ks[6] = {128, 128, 64, 64, 64, 128};
    const int Ms[6] = {128, 64, 64, 64, 128, 128};
    const int Off[6] = {0, 16384, 24576, 28672, 32768, 40960};
    int s = g >> 6;
    int id = (g & 63) * 256 + t;
    int K = Ks[s], M = Ms[s];
    if (id >= K * M) return;
    int ms = (M == 128) ? 7 : 6;
    int k = id >> ms, c = id & (M - 1);
    int chunk = k >> 5, j = k & 7, lq = (k >> 3) & 3;
    int ct = c >> 4, ln = (c & 15) + (lq << 4);
    out[Off[s] + (chunk * (M >> 4) + ct) * 512 + ln * 8 + j] = f2bf(pa.w[s][id]);
}

// ---------------- k1: bin edges by dst>>9 (blocks [0,C)) + weight pack (blocks [C,C+384)) ----------------

__global__ __launch_bounds__(256) void k_bin_pack(const int* __restrict__ ei, int E, int NB, int C,
                                                  int* __restrict__ bin_cursor, u32* __restrict__ binned,
                                                  PackArgs pa, u16* __restrict__ wpk) {
    __shared__ int sh[256];  // hist[128] | base_l[128]
    const int t = threadIdx.x;
    if ((int)blockIdx.x >= C) {
        pack_body(pa, wpk, blockIdx.x - C, t);
        return;
    }
    int* hist = sh;
    int* base_l = sh + 128;
    const int e0 = blockIdx.x * 4096;
    int sreg[16], dreg[16];
#pragma unroll
    for (int j = 0; j < 16; ++j) {
        int e = e0 + j * 256 + t;
        if (e < E) {
            sreg[j] = ei[e];
            dreg[j] = ei[E + e];
        } else {
            dreg[j] = -1;
        }
    }
    if (t < NB) hist[t] = 0;
    __syncthreads();
#pragma unroll
    for (int j = 0; j < 16; ++j)
        if (dreg[j] >= 0) atomicAdd(&hist[dreg[j] >> BSHIFT], 1);
    __syncthreads();
    if (t < NB) {
        base_l[t] = atomicAdd(&bin_cursor[t], hist[t]);
        hist[t] = 0;  // reuse as local fill
    }
    __syncthreads();
#pragma unroll
    for (int j = 0; j < 16; ++j)
        if (dreg[j] >= 0) {
            int b = dreg[j] >> BSHIFT;
            int pos = base_l[b] + atomicAdd(&hist[b], 1);
            if (pos < BCAP) binned[(size_t)b * BCAP + pos] = ((u32)(dreg[j] & (BSIZE - 1)) << 17) | (u32)sreg[j];
        }
}

// ---------------- MFMA GEMM tile body (forceinlined; B fragments from global, no LDS) ----------------

template <int K, int M, int RT, int NSET, bool XBF16, bool OUT_BF16, bool BREL>
__device__ __forceinline__ void gemm_tile(const void* __restrict__ Xv, const u16* __restrict__ Bpk,
                                          const float* __restrict__ b0, const float* __restrict__ b1,
                                          const float* __restrict__ eps,
                                          void* __restrict__ Y0, float* __restrict__ Y1,
                                          u16* __restrict__ Z, int N, int col0, int row0, int t) {
    constexpr int CH = K / 32;
    constexpr int TPM = M >> 4;
    constexpr int SETSTRIDE = CH * TPM * 512;
    const int lane = t & 63, w = t >> 6;
    const int l15 = lane & 15, q = lane >> 4;

    s16x8 Bfr[NSET * CH * 4];
#pragma unroll
    for (int s = 0; s < NSET; ++s)
#pragma unroll
        for (int ch = 0; ch < CH; ++ch)
#pragma unroll
            for (int ct = 0; ct < 4; ++ct)
                Bfr[(s * CH + ch) * 4 + ct] =
                    *(const s16x8*)&Bpk[(size_t)s * SETSTRIDE + ((ch * TPM) + (col0 >> 4) + ct) * 512 + lane * 8];

    f32x4 acc[NSET][RT][4];
#pragma unroll
    for (int s = 0; s < NSET; ++s)
#pragma unroll
        for (int rt = 0; rt < RT; ++rt)
#pragma unroll
            for (int ct = 0; ct < 4; ++ct) acc[s][rt][ct] = 0.f;

#pragma unroll
    for (int ch = 0; ch < CH; ++ch) {
#pragma unroll
        for (int rt = 0; rt < RT; ++rt) {
            int r = row0 + (w * RT + rt) * 16 + l15;
            r = r < N ? r : N - 1;
            s16x8 ah, al;
            if (XBF16) {
                ah = *(const s16x8*)((const u16*)Xv + (size_t)r * K + (ch << 5) + (q << 3));
            } else {
                const float* xp = (const float*)Xv + (size_t)r * K + (ch << 5) + (q << 3);
                f32x4 x0 = *(const f32x4*)xp;
                f32x4 x1 = *(const f32x4*)(xp + 4);
                ah = pack_hi(x0, x1);
                al = pack_lo(x0, x1);
            }
#pragma unroll
            for (int s = 0; s < NSET; ++s)
#pragma unroll
                for (int ct = 0; ct < 4; ++ct) {
                    int fb = (s * CH + ch) * 4 + ct;
                    acc[s][rt][ct] = __builtin_amdgcn_mfma_f32_16x16x32_bf16(ah, Bfr[fb], acc[s][rt][ct], 0, 0, 0);
                    if (!XBF16)
                        acc[s][rt][ct] = __builtin_amdgcn_mfma_f32_16x16x32_bf16(al, Bfr[fb], acc[s][rt][ct], 0, 0, 0);
                }
        }
    }

#pragma unroll
    for (int rt = 0; rt < RT; ++rt)
#pragma unroll
        for (int ct = 0; ct < 4; ++ct)
#pragma unroll
            for (int reg = 0; reg < 4; ++reg) {
                int row = row0 + (w * RT + rt) * 16 + q * 4 + reg;
                if (row >= N) continue;
                int col = col0 + ct * 16 + l15;
                if (NSET == 1) {
                    float v = acc[0][rt][ct][reg];
                    if (BREL) v = fmaxf(v + b0[col], 0.f);
                    if (OUT_BF16)
                        ((u16*)Y0)[(size_t)row * M + col] = f2bf(v);
                    else
                        ((float*)Y0)[(size_t)row * M + col] = v;
                } else {
                    float mu = acc[0][rt][ct][reg] + b0[col];
                    float lv = acc[1][rt][ct][reg] + b1[col];
                    size_t o = (size_t)row * 64 + col;
                    ((float*)Y0)[o] = mu;
                    Y1[o] = lv;
                    Z[o] = f2bf(mu + eps[o] * expf(0.5f * lv));
                }
            }
}

// standalone GEMM wrapper (k5, k7, k9, k10)
template <int K, int M, int RT, int NSET, bool XBF16, bool OUT_BF16, bool BREL>
__global__ __launch_bounds__(256, 3) void k_gemm(const void* __restrict__ Xv, const u16* __restrict__ Bpk,
                                                 const float* __restrict__ b0, const float* __restrict__ b1,
                                                 const float* __restrict__ eps,
                                                 void* __restrict__ Y0, float* __restrict__ Y1,
                                                 u16* __restrict__ Z, int N) {
    gemm_tile<K, M, RT, NSET, XBF16, OUT_BF16, BREL>(Xv, Bpk, b0, b1, eps, Y0, Y1, Z, N,
                                                     blockIdx.x * 64, blockIdx.y * (RT * 64), threadIdx.x);
}

// ---------------- k2: per-bin count+alloc (blocks [0,NB)) + GEMM1 col-half 0 (blocks [NB,..)) ----------------

__global__ __launch_bounds__(256, 3) void k_cnt_gemm1(const u32* __restrict__ binned,
                                                      const int* __restrict__ bin_cursor, int N, int NB,
                                                      int* __restrict__ cnt, float* __restrict__ dinv,
                                                      int* __restrict__ row_start, int* __restrict__ cursor,
                                                      const float* __restrict__ x, const u16* __restrict__ wpk,
                                                      u16* __restrict__ R1) {
    __shared__ int cnt_l[BSIZE];
    __shared__ int wave_sum[5];
    __shared__ int base_s;
    const int t = threadIdx.x;
    const int b = blockIdx.x;
    if (b >= NB) {
        gemm_tile<128, 128, 2, 1, false, true, false>(x, wpk, nullptr, nullptr, nullptr, R1, nullptr, nullptr,
                                                      N, 0, (b - NB) * 128, t);
        return;
    }
    const int lane = t & 63, w = t >> 6;
    cnt_l[t] = 0;
    cnt_l[t + 256] = 0;
    __syncthreads();
    const int n = min(bin_cursor[b], BCAP);
    for (int i = t; i < n; i += 256) atomicAdd(&cnt_l[binned[(size_t)b * BCAP + i] >> 17], 1);
    __syncthreads();
    int c0 = cnt_l[2 * t], c1 = cnt_l[2 * t + 1];
    int p0 = (c0 + 7) & ~7, p1 = (c1 + 7) & ~7;
    int s = p0 + p1;
    int incl = s;
#pragma unroll
    for (int o = 1; o < 64; o <<= 1) {
        int v = __shfl_up(incl, o, 64);
        if (lane >= o) incl += v;
    }
    if (lane == 63) wave_sum[w] = incl;
    __syncthreads();
    if (t == 0) {
        int acc = 0;
#pragma unroll
        for (int i = 0; i < 4; ++i) {
            int v = wave_sum[i];
            wave_sum[i] = acc;
            acc += v;
        }
        base_s = atomicAdd(cursor, acc);
    }
    __syncthreads();
    int excl = incl - s + wave_sum[w] + base_s;
    int v0 = b * BSIZE + 2 * t;
    if (v0 < N) {
        cnt[v0] = c0;
        dinv[v0] = rsqrtf((float)(c0 + 1));
        row_start[v0] = excl;
    }
    if (v0 + 1 < N) {
        cnt[v0 + 1] = c1;
        dinv[v0 + 1] = rsqrtf((float)(c1 + 1));
        row_start[v0 + 1] = excl + p0;
    }
}

// ---------------- k3: per-bin scatter (blocks [0,NB)) + GEMM1 col-half 1 (blocks [NB,..)) ----------------

__global__ __launch_bounds__(256, 3) void k_scat_gemm1(const u32* __restrict__ binned,
                                                       const int* __restrict__ bin_cursor,
                                                       const int* __restrict__ row_start,
                                                       const float* __restrict__ dinv, int N, int NB,
                                                       int2* __restrict__ edges,
                                                       const float* __restrict__ x, const u16* __restrict__ wpk,
                                                       u16* __restrict__ R1) {
    __shared__ float dv_l[BSIZE];
    __shared__ int rs_l[BSIZE];
    __shared__ int fill_l[BSIZE];
    const int t = threadIdx.x;
    const int b = blockIdx.x;
    if (b >= NB) {
        gemm_tile<128, 128, 2, 1, false, true, false>(x, wpk, nullptr, nullptr, nullptr, R1, nullptr, nullptr,
                                                      N, 64, (b - NB) * 128, t);
        return;
    }
#pragma unroll
    for (int hh = 0; hh < 2; ++hh) {
        int d = t + hh * 256;
        int v = b * BSIZE + d;
        bool ok = v < N;
        dv_l[d] = ok ? dinv[v] : 0.f;
        rs_l[d] = ok ? row_start[v] : 0;
        fill_l[d] = 0;
    }
    __syncthreads();
    const int n = min(bin_cursor[b], BCAP);
    for (int i = t; i < n; i += 256) {
        u32 e = binned[(size_t)b * BCAP + i];
        int dl = e >> 17;
        int src = e & 0x1FFFF;
        float wgt = dinv[src] * dv_l[dl];
        int pos = rs_l[dl] + atomicAdd(&fill_l[dl], 1);
        edges[pos] = make_int2(src, __float_as_int(wgt));
    }
    __syncthreads();
#pragma unroll
    for (int hh = 0; hh < 2; ++hh) {
        int d = t + hh * 256;
        int v = b * BSIZE + d;
        if (v >= N) continue;
        int c = fill_l[d];
        int pc = (c + 7) & ~7;
        for (int j = c; j < pc; ++j) edges[rs_l[d] + j] = make_int2(0, 0);
    }
}

// ---------------- CSR aggregation, padded buckets, 8-deep gather pipeline ----------------

template <bool RELU, bool OUT_BF16>
__global__ __launch_bounds__(256) void k_agg128(const u16* __restrict__ hin, const int2* __restrict__ edges,
                                                const int* __restrict__ row_start, const int* __restrict__ cnt,
                                                const float* __restrict__ dinv, const float* __restrict__ bias,
                                                void* __restrict__ out, int N) {
    const int v = blockIdx.x * 4 + (threadIdx.x >> 6);
    const int lane = threadIdx.x & 63;
    if (v >= N) return;
    const int start = __builtin_amdgcn_readfirstlane(row_start[v]);
    const int c = __builtin_amdgcn_readfirstlane(cnt[v]);
    const int pc = (c + 7) & ~7;
    const u32* hp = (const u32*)hin;
    float a0 = 0.f, a1 = 0.f;
    if (pc) {
        int2 e[8];
#pragma unroll
        for (int j = 0; j < 8; ++j) e[j] = edges[start + j];
        for (int i = 0; i < pc; i += 8) {
            u32 h[8];
            float wv[8];
#pragma unroll
            for (int j = 0; j < 8; ++j) {
                h[j] = hp[(size_t)e[j].x * 64 + lane];
                wv[j] = __int_as_float(e[j].y);
            }
            if (i + 8 < pc) {
#pragma unroll
                for (int j = 0; j < 8; ++j) e[j] = edges[start + i + 8 + j];
            }
#pragma unroll
            for (int j = 0; j < 8; ++j) {
                a0 = fmaf(wv[j], bf2f((u16)h[j]), a0);
                a1 = fmaf(wv[j], bf2f((u16)(h[j] >> 16)), a1);
            }
        }
    }
    float dv = dinv[v], sw = dv * dv;
    u32 hs = hp[(size_t)v * 64 + lane];
    a0 = fmaf(sw, bf2f((u16)hs), a0);
    a1 = fmaf(sw, bf2f((u16)(hs >> 16)), a1);
    float2 bp = ((const float2*)bias)[lane];
    a0 += bp.x;
    a1 += bp.y;
    if (RELU) { a0 = fmaxf(a0, 0.f); a1 = fmaxf(a1, 0.f); }
    if (OUT_BF16)
        ((u32*)out)[(size_t)v * 64 + lane] = (u32)f2bf(a0) | ((u32)f2bf(a1) << 16);
    else
        ((float2*)out)[(size_t)v * 64 + lane] = make_float2(a0, a1);
}

template <bool HASB>
__global__ __launch_bounds__(256) void k_agg64(const u16* __restrict__ hin, const int2* __restrict__ edges,
                                               const int* __restrict__ row_start, const int* __restrict__ cnt,
                                               const float* __restrict__ dinv, const float* __restrict__ bias,
                                               float* __restrict__ out, int N) {
    const int v = blockIdx.x * 4 + (threadIdx.x >> 6);
    const int lane = threadIdx.x & 63;
    if (v >= N) return;
    const int start = __builtin_amdgcn_readfirstlane(row_start[v]);
    const int c = __builtin_amdgcn_readfirstlane(cnt[v]);
    const int pc = (c + 7) & ~7;
    float a0 = 0.f;
    if (pc) {
        int2 e[8];
#pragma unroll
        for (int j = 0; j < 8; ++j) e[j] = edges[start + j];
        for (int i = 0; i < pc; i += 8) {
            u16 h[8];
            float wv[8];
#pragma unroll
            for (int j = 0; j < 8; ++j) {
                h[j] = hin[(size_t)e[j].x * 64 + lane];
                wv[j] = __int_as_float(e[j].y);
            }
            if (i + 8 < pc) {
#pragma unroll
                for (int j = 0; j < 8; ++j) e[j] = edges[start + i + 8 + j];
            }
#pragma unroll
            for (int j = 0; j < 8; ++j) a0 = fmaf(wv[j], bf2f(h[j]), a0);
        }
    }
    float dv = dinv[v];
    a0 = fmaf(dv * dv, bf2f(hin[(size_t)v * 64 + lane]), a0);
    if (HASB) a0 += bias[lane];
    out[(size_t)v * 64 + lane] = a0;
}

// ---------------- launch ----------------

extern "C" void kernel_launch(void* const* d_in, const int* in_sizes, int n_in,
                              void* d_out, int out_size, void* d_ws, size_t ws_size,
                              hipStream_t stream) {
    const float* x = (const float*)d_in[0];
    const int* ei = (const int*)d_in[1];
    const float* eps = (const float*)d_in[2];
    const float* We1 = (const float*)d_in[3];
    const float* be1 = (const float*)d_in[4];
    const float* We2 = (const float*)d_in[5];
    const float* be2 = (const float*)d_in[6];
    const float* Wmu = (const float*)d_in[7];
    const float* bmu = (const float*)d_in[8];
    const float* Wlv = (const float*)d_in[9];
    const float* blv = (const float*)d_in[10];
    const float* Wd1 = (const float*)d_in[11];
    const float* bd1 = (const float*)d_in[12];
    const float* Wd2 = (const float*)d_in[13];
    const float* bd2 = (const float*)d_in[14];

    const int N = in_sizes[0] / 128;  // 50000
    const int E = in_sizes[1] / 2;    // 800000
    const int ECAP = E + 8 * N;
    const int NB = (N + BSIZE - 1) >> BSHIFT;  // 98
    const int C = (E + 4095) / 4096;           // 196 bin blocks

    // ws: bin_cursor(128) | cursor(1)+pad(127) | dinv(N) | row_start(N) | cnt(N)
    //   | edges(ECAP int2) | R1(u16 N*128) | AZu(u16 N*128, aliases binned u32[NB*BCAP] + AZf) | B2(u16 N*128) | Wpk
    int* bin_cursor = (int*)d_ws;
    int* cursor = bin_cursor + 128;
    float* dinv = (float*)(bin_cursor + 256);
    int* row_start = (int*)(dinv + N);
    int* cnt = row_start + N;
    int2* edges = (int2*)(cnt + N);
    u16* R1 = (u16*)(edges + ECAP);
    u16* AZu = R1 + (size_t)N * 128;
    u16* B2 = AZu + (size_t)N * 128;
    u16* Wpk = B2 + (size_t)N * 128;
    float* AZf = (float*)AZu;
    u32* binned = (u32*)AZu;  // alias: dead once scatter completes

    float* out_d = (float*)d_out;
    float* out_mu = out_d + (size_t)N * 128;
    float* out_lv = out_mu + (size_t)N * 64;
    float* H2 = out_d;

    hipMemsetAsync(d_ws, 0, 256 * 4, stream);  // bin_cursor + cursor

    PackArgs pa;
    pa.w[0] = We1; pa.w[1] = We2; pa.w[2] = Wmu; pa.w[3] = Wlv; pa.w[4] = Wd1; pa.w[5] = Wd2;

    const int RB128 = (N + 127) / 128;  // 391
    const int RB64 = (N + 63) / 64;     // 782
    const int AB = (N + 3) / 4;         // 12500

    // k1: bin + weight pack
    k_bin_pack<<<dim3(C + 384), dim3(256), 0, stream>>>(ei, E, NB, C, bin_cursor, binned, pa, Wpk);
    // k2: cnt+alloc  ||  encoder GEMM1 cols 0-63
    k_cnt_gemm1<<<dim3(NB + RB128), dim3(256), 0, stream>>>(binned, bin_cursor, N, NB, cnt, dinv, row_start,
                                                            cursor, x, Wpk, R1);
    // k3: scatter  ||  encoder GEMM1 cols 64-127
    k_scat_gemm1<<<dim3(NB + RB128), dim3(256), 0, stream>>>(binned, bin_cursor, row_start, dinv, N, NB,
                                                             edges, x, Wpk, R1);
    // k4: encoder agg1 + be1 + relu -> AZu (bf16)
    k_agg128<true, true><<<dim3(AB), dim3(256), 0, stream>>>(R1, edges, row_start, cnt, dinv, be1, AZu, N);
    // k5: encoder GEMM2 AZu@We2 -> R1 (bf16)
    k_gemm<128, 64, 1, 1, true, true, false><<<dim3(1, RB64), dim3(256), 0, stream>>>(AZu, Wpk + 16384, nullptr, nullptr, nullptr, R1, nullptr, nullptr, N);
    // k6: encoder agg2 + be2 -> H2 (f32)
    k_agg64<true><<<dim3(AB), dim3(256), 0, stream>>>(R1, edges, row_start, cnt, dinv, be2, H2, N);
    // k7: mu / logvar / z
    k_gemm<64, 64, 1, 2, false, false, false><<<dim3(1, RB64), dim3(256), 0, stream>>>(H2, Wpk + 24576, bmu, blv, eps, out_mu, out_lv, R1, N);
    // k8: decoder agg (agg-first) z -> AZf (f32)
    k_agg64<false><<<dim3(AB), dim3(256), 0, stream>>>(R1, edges, row_start, cnt, dinv, nullptr, AZf, N);
    // k9: decoder GEMM1 AZf@Wd1 + bd1 + relu -> B2 (bf16)  [separate buffer: no in-place race]
    k_gemm<64, 128, 2, 1, false, true, true><<<dim3(2, RB128), dim3(256), 0, stream>>>(AZf, Wpk + 32768, bd1, nullptr, nullptr, B2, nullptr, nullptr, N);
    // k10: decoder GEMM2 B2@Wd2 -> R1 (bf16)
    k_gemm<128, 128, 2, 1, true, true, false><<<dim3(2, RB128), dim3(256), 0, stream>>>(B2, Wpk + 40960, nullptr, nullptr, nullptr, R1, nullptr, nullptr, N);
    // k11: final agg + bd2 -> out_d (f32)
    k_agg128<false, false><<<dim3(AB), dim3(256), 0, stream>>>(R1, edges, row_start, cnt, dinv, bd2, out_d, N);
}